// Round 3
// baseline (766.143 us; speedup 1.0000x reference)
//
#include <hip/hip_runtime.h>

// Memory-bound problem: 512 MiB read + 32 MiB write -> ~86 us floor @6.3 TB/s.
// R1 (direct loads): 167 us, TA 64-line divergence throttles issue.
// R2 (coalesced LDS, conflict-free): 167 us, burst->drain->compute duty cycle
//   caps per-CU BW at ~12.6 GB/s (half of fair share).
// R3: persistent blocks (2/CU), cross-tile register prefetch: next tile's 16
//   global loads are in flight during current tile's LDS-write + compute, so
//   outstanding bytes never drop to zero for long.

__global__ __launch_bounds__(256, 2) void surrogate_kernel(
    const float* __restrict__ img1, const float* __restrict__ img2,
    const float* __restrict__ Wc,   // (16,4) row-major
    const float* __restrict__ Wl,   // (16,4) row-major
    float* __restrict__ out,
    int B)
{
    // 256 images * 16 float4 chunks = 64 KiB; chunk c of image i lives at
    // tile[i*16 + (c ^ (i & 15))] -> conflict-free for both phases (R2: 0).
    __shared__ float4 tile[256 * 16];

    const int t   = threadIdx.x;
    const int q   = t >> 4;     // image-within-group this thread stages
    const int cth = t & 15;     // chunk index this thread stages
    const int blocksPerInput = B >> 8;       // B % 256 == 0
    const int nT = 2 * blocksPerInput;

    const float4* wc4 = (const float4*)Wc;
    const float4* wl4 = (const float4*)Wl;

    int tt = blockIdx.x;

    // Prologue: issue first tile's loads.
    float4 r[16];
    {
        const float4* src4 = (tt < blocksPerInput)
            ? ((const float4*)img1 + (size_t)tt * 4096)
            : ((const float4*)img2 + (size_t)(tt - blocksPerInput) * 4096);
#pragma unroll
        for (int k = 0; k < 16; ++k) r[k] = src4[k * 256 + t];
    }

    while (true) {
        // Stage current tile (waits the loads), swizzled.
#pragma unroll
        for (int k = 0; k < 16; ++k)
            tile[(16 * k + q) * 16 + (cth ^ q)] = r[k];   // (16k+q)&15 == q
        __syncthreads();

        const int cur = tt;
        tt += (int)gridDim.x;
        const bool more = tt < nT;             // block-uniform
        if (more) {
            // Prefetch next tile NOW -> in flight during compute below.
            const float4* src4 = (tt < blocksPerInput)
                ? ((const float4*)img1 + (size_t)tt * 4096)
                : ((const float4*)img2 + (size_t)(tt - blocksPerInput) * 4096);
#pragma unroll
            for (int k = 0; k < 16; ++k) r[k] = src4[k * 256 + t];
        }

        // ---- compute: thread t owns image t of this tile ----
        float a1[4][4];
#pragma unroll
        for (int p = 0; p < 4; ++p)
#pragma unroll
            for (int c = 0; c < 4; ++c) a1[p][c] = 0.0f;

        const int key  = t & 15;
        const int base = t * 16;
#pragma unroll
        for (int c = 0; c < 16; ++c) {               // c uniform -> static idx
            const float4 v = tile[base + (c ^ key)]; // chunk c of image t
            const int row = c >> 1;
            const int p   = ((row >> 2) << 1) | (c & 1);
            const int rr  = row & 3;
            const float4 w0 = wc4[rr * 4 + 0];
            const float4 w1 = wc4[rr * 4 + 1];
            const float4 w2 = wc4[rr * 4 + 2];
            const float4 w3 = wc4[rr * 4 + 3];
            a1[p][0] = fmaf(v.x, w0.x, a1[p][0]);
            a1[p][1] = fmaf(v.x, w0.y, a1[p][1]);
            a1[p][2] = fmaf(v.x, w0.z, a1[p][2]);
            a1[p][3] = fmaf(v.x, w0.w, a1[p][3]);
            a1[p][0] = fmaf(v.y, w1.x, a1[p][0]);
            a1[p][1] = fmaf(v.y, w1.y, a1[p][1]);
            a1[p][2] = fmaf(v.y, w1.z, a1[p][2]);
            a1[p][3] = fmaf(v.y, w1.w, a1[p][3]);
            a1[p][0] = fmaf(v.z, w2.x, a1[p][0]);
            a1[p][1] = fmaf(v.z, w2.y, a1[p][1]);
            a1[p][2] = fmaf(v.z, w2.z, a1[p][2]);
            a1[p][3] = fmaf(v.z, w2.w, a1[p][3]);
            a1[p][0] = fmaf(v.w, w3.x, a1[p][0]);
            a1[p][1] = fmaf(v.w, w3.y, a1[p][1]);
            a1[p][2] = fmaf(v.w, w3.z, a1[p][2]);
            a1[p][3] = fmaf(v.w, w3.w, a1[p][3]);
        }

        float co[16];
#pragma unroll
        for (int p = 0; p < 4; ++p)
#pragma unroll
            for (int c = 0; c < 4; ++c) {
                float tv = fmaxf(a1[p][c], 0.0f) * 0.015625f;
                co[p * 4 + c] = fminf(fmaxf(tv, -128.0f), 127.0f);
            }

        float a2[4] = {0.0f, 0.0f, 0.0f, 0.0f};
#pragma unroll
        for (int j = 0; j < 16; ++j) {
            const float4 w = wl4[j];
            a2[0] = fmaf(co[j], w.x, a2[0]);
            a2[1] = fmaf(co[j], w.y, a2[1]);
            a2[2] = fmaf(co[j], w.z, a2[2]);
            a2[3] = fmaf(co[j], w.w, a2[3]);
        }

        float4 o;
        o.x = fminf(fmaxf(a2[0] * 0.015625f, -128.0f), 127.0f);
        o.y = fminf(fmaxf(a2[1] * 0.015625f, -128.0f), 127.0f);
        o.z = fminf(fmaxf(a2[2] * 0.015625f, -128.0f), 127.0f);
        o.w = fminf(fmaxf(a2[3] * 0.015625f, -128.0f), 127.0f);
        ((float4*)out)[(size_t)cur * 256 + t] = o;   // == second*B + bid*256 + t

        if (!more) break;
        __syncthreads();   // protect LDS before next tile's writes
    }
}

extern "C" void kernel_launch(void* const* d_in, const int* in_sizes, int n_in,
                              void* d_out, int out_size, void* d_ws, size_t ws_size,
                              hipStream_t stream) {
    const float* img1 = (const float*)d_in[0];
    const float* img2 = (const float*)d_in[1];
    const float* Wc   = (const float*)d_in[2];
    const float* Wl   = (const float*)d_in[3];
    float* out = (float*)d_out;

    const int B = in_sizes[0] / 64;   // images per input (1<<20)
    const int nT = 2 * (B >> 8);
    int grid = 512;                   // 2 persistent blocks per CU
    if (grid > nT) grid = nT;
    hipLaunchKernelGGL(surrogate_kernel, dim3(grid), dim3(256), 0, stream,
                       img1, img2, Wc, Wl, out, B);
}